// Round 5
// baseline (61.637 us; speedup 1.0000x reference)
//
#include <hip/hip_runtime.h>
#include <hip/hip_bf16.h>
#include <math.h>

#define BATCH 4096
#define TWO_B 8192
#define DIM 128
#define NB 16384
#define COS_EPS 1e-8f
#define LOSS_EPS 1e-6f
// 1/TEMP ; log2(e)/TEMP ; sqrt(log2(e)/TEMP)
#define INV_TEMP 14.285714285714286f
#define EXP2_SCALE 20.60992915555662f
#define SQRT_EXP2_SCALE 4.5398166f

#define N_POS (TWO_B + 8 * BATCH)   // 40960 positive dots
#define RED_BLOCKS 64
#define GRAM_BLOCKS 1056            // #{(I,J): I<32, 2I<=J<64}

typedef __attribute__((ext_vector_type(8))) short bf16x8;
typedef __attribute__((ext_vector_type(4))) float f32x4;

__device__ __forceinline__ float fast_exp2(float x) {
#if __has_builtin(__builtin_amdgcn_exp2f)
  return __builtin_amdgcn_exp2f(x);
#else
  float r;
  asm("v_exp_f32 %0, %1" : "=v"(r) : "v"(x));
  return r;
#endif
}

// ---------------- K1: normalize rows -> bf16 za_n (pre-scaled), inv norms; zero rowsum ----------------
__global__ __launch_bounds__(256) void k_normalize(
    const float* __restrict__ z1, const float* __restrict__ z2,
    const float* __restrict__ zn,
    __hip_bfloat16* __restrict__ za_n, float* __restrict__ inv_za,
    float* __restrict__ inv_zn, float* __restrict__ rowsum) {
  if (blockIdx.x < 32) rowsum[blockIdx.x * 256 + threadIdx.x] = 0.0f;  // fused zero
  int wave = (blockIdx.x * blockDim.x + threadIdx.x) >> 6;
  int lane = threadIdx.x & 63;
  if (wave >= TWO_B + NB) return;
  const float* src;
  if (wave < BATCH) src = z1 + (size_t)wave * DIM;
  else if (wave < TWO_B) src = z2 + (size_t)(wave - BATCH) * DIM;
  else src = zn + (size_t)(wave - TWO_B) * DIM;
  float2 v = ((const float2*)src)[lane];
  float ss = v.x * v.x + v.y * v.y;
#pragma unroll
  for (int m = 1; m < 64; m <<= 1) ss += __shfl_xor(ss, m, 64);
  float inv = 1.0f / fmaxf(sqrtf(ss), COS_EPS);
  if (wave < TWO_B) {
    if (lane == 0) inv_za[wave] = inv;
    float s = inv * SQRT_EXP2_SCALE;   // fold exp2 scale into the data
    __hip_bfloat162 o;
    o.x = __float2bfloat16(v.x * s);
    o.y = __float2bfloat16(v.y * s);
    ((__hip_bfloat162*)(za_n + (size_t)wave * DIM))[lane] = o;
  } else {
    if (lane == 0) inv_zn[wave - TWO_B] = inv;
  }
}

// ---------------- K2: positives, 8 dots per wave (8-lane sub-groups), fp32 exact ----------------
__device__ __forceinline__ const float* za_row(const float* z1, const float* z2, int r) {
  return r < BATCH ? z1 + (size_t)r * DIM : z2 + (size_t)(r - BATCH) * DIM;
}

__global__ __launch_bounds__(256) void k_positives(
    const float* __restrict__ z1, const float* __restrict__ z2,
    const float* __restrict__ zn, const float* __restrict__ inv_za,
    const float* __restrict__ inv_zn, float* __restrict__ pos_partial) {
  int wv = (blockIdx.x * 256 + threadIdx.x) >> 6;
  int lane = threadIdx.x & 63;
  int p = lane >> 3, sub = lane & 7;
  int idx = wv * 8 + p;
  if (idx >= N_POS) return;
  const float *pa, *pb;
  float invprod;
  bool is_aug;
  if (idx < TWO_B) {
    int r = idx, q = (idx + BATCH) & (TWO_B - 1);
    pa = za_row(z1, z2, r);
    pb = za_row(z1, z2, q);
    invprod = inv_za[r] * inv_za[q];
    is_aug = true;
  } else {
    int k = idx - TWO_B;
    int zr, zc;
    if (k < BATCH)                { zr = BATCH + k; zc = k; }
    else if (k < BATCH + TWO_B)   { int j = k - BATCH;             zr = j; zc = j; }
    else if (k < BATCH + 2*TWO_B) { int j = k - BATCH - TWO_B;     zr = j; zc = j + BATCH; }
    else if (k < BATCH + 3*TWO_B) { int j = k - BATCH - 2*TWO_B;   zr = j; zc = j + 2*BATCH; }
    else                          { int j = k - BATCH - 3*TWO_B;   zr = j; zc = j + 3*BATCH; }
    pa = za_row(z1, z2, zr);
    pb = zn + (size_t)zc * DIM;
    invprod = inv_za[zr] * inv_zn[zc];
    is_aug = false;
  }
  float d = 0.0f;
#pragma unroll
  for (int j = 0; j < 4; ++j) {
    float4 a = ((const float4*)pa)[sub + j * 8];
    float4 b = ((const float4*)pb)[sub + j * 8];
    d += a.x * b.x + a.y * b.y + a.z * b.z + a.w * b.w;
  }
  d += __shfl_xor(d, 1, 64);
  d += __shfl_xor(d, 2, 64);
  d += __shfl_xor(d, 4, 64);
  if (sub == 0) {
    float sim = d * invprod;
    pos_partial[idx] = is_aug ? (4.0f * sim * INV_TEMP)
                              : (fminf(sim, 1.0f) * INV_TEMP);
  }
}

// ---------------- K3: symmetric Gram, 256x128 tiles, strict-upper mask, row+col sums ----------------
// grid: 1056 blocks = {(I,J): I in [0,32), J in [2I,64)}; block 512 thr = 8 waves of 64x64.
// LDS 48 KB (A 256x64k + B 128x64k bf16, K split in 2 halves) -> 2 blocks/CU.
__global__ __launch_bounds__(512, 4) void k_gram(
    const __hip_bfloat16* __restrict__ za_n, float* __restrict__ rowsum) {
  __shared__ char ldsA[32768];
  __shared__ char ldsB[16384];
  const int t = threadIdx.x;
  int rem = blockIdx.x, I = 0;
  while (rem >= 64 - 2 * I) { rem -= 64 - 2 * I; ++I; }
  const int J = 2 * I + rem;
  const int Ibase = I * 256, Jbase = J * 128;
  const char* za8 = (const char*)za_n;   // byte view; row stride 256 B

  const int w = t >> 6, lane = t & 63;
  const int wr = w & 3, wc = w >> 2;     // 4 row strips x 2 col strips of 64
  const int lhi = lane >> 4, llo = lane & 15;

  f32x4 acc[4][4];
#pragma unroll
  for (int rt = 0; rt < 4; ++rt)
#pragma unroll
    for (int ct = 0; ct < 4; ++ct) acc[rt][ct] = (f32x4)0.0f;

  for (int h = 0; h < 2; ++h) {
    if (h) __syncthreads();              // half-0 reads complete before overwrite
    // stage A half: 256 rows x 128 B, XOR-swizzled
#pragma unroll
    for (int it = 0; it < 4; ++it) {
      int e = it * 8192 + t * 16;
      int row = e >> 7, kb = e & 127;
      uint4 d = *(const uint4*)(za8 + (size_t)(Ibase + row) * 256 + h * 128 + kb);
      *(uint4*)(ldsA + row * 128 + (kb ^ ((row & 7) << 4))) = d;
    }
    // stage B half: 128 rows x 128 B
#pragma unroll
    for (int it = 0; it < 2; ++it) {
      int e = it * 8192 + t * 16;
      int row = e >> 7, kb = e & 127;
      uint4 d = *(const uint4*)(za8 + (size_t)(Jbase + row) * 256 + h * 128 + kb);
      *(uint4*)(ldsB + row * 128 + (kb ^ ((row & 7) << 4))) = d;
    }
    __syncthreads();
#pragma unroll
    for (int ks = 0; ks < 2; ++ks) {
      const int koff = ks * 64 + lhi * 16;
      bf16x8 af[4], bfr[4];
#pragma unroll
      for (int rt = 0; rt < 4; ++rt) {
        int row = wr * 64 + rt * 16 + llo;
        af[rt] = *(const bf16x8*)(ldsA + row * 128 + (koff ^ ((row & 7) << 4)));
      }
#pragma unroll
      for (int ct = 0; ct < 4; ++ct) {
        int row = wc * 64 + ct * 16 + llo;
        bfr[ct] = *(const bf16x8*)(ldsB + row * 128 + (koff ^ ((row & 7) << 4)));
      }
#pragma unroll
      for (int rt = 0; rt < 4; ++rt)
#pragma unroll
        for (int ct = 0; ct < 4; ++ct)
          acc[rt][ct] = __builtin_amdgcn_mfma_f32_16x16x32_bf16(
              af[rt], bfr[ct], acc[rt][ct], 0, 0, 0);
    }
  }

  // epilogue: exp2, strict-upper mask (handles diagonal AND straddling tiles), row+col sums
  float cp[4] = {0.0f, 0.0f, 0.0f, 0.0f};
#pragma unroll
  for (int rt = 0; rt < 4; ++rt) {
    const int growb = Ibase + wr * 64 + rt * 16 + lhi * 4;   // + g
    float rp[4] = {0.0f, 0.0f, 0.0f, 0.0f};
#pragma unroll
    for (int ct = 0; ct < 4; ++ct) {
      const int gcol = Jbase + wc * 64 + ct * 16 + llo;
#pragma unroll
      for (int g = 0; g < 4; ++g) {
        float e = fast_exp2(acc[rt][ct][g]);
        e = (gcol > growb + g) ? e : 0.0f;   // strict upper triangle only
        rp[g] += e;
        cp[ct] += e;
      }
    }
#pragma unroll
    for (int g = 0; g < 4; ++g) {
      float s = rp[g];
      s += __shfl_xor(s, 1, 64);
      s += __shfl_xor(s, 2, 64);
      s += __shfl_xor(s, 4, 64);
      s += __shfl_xor(s, 8, 64);
      if (llo == 0) atomicAdd(&rowsum[growb + g], s);
    }
  }
#pragma unroll
  for (int ct = 0; ct < 4; ++ct) {
    float s = cp[ct];
    s += __shfl_xor(s, 16, 64);
    s += __shfl_xor(s, 32, 64);
    if (lhi == 0) atomicAdd(&rowsum[Jbase + wc * 64 + ct * 16 + llo], s);
  }
}

// ---------------- K4a: parallel reduction stage 1 ----------------
__global__ __launch_bounds__(256) void k_reduce(
    const float* __restrict__ rowsum, const float* __restrict__ pos_partial,
    float* __restrict__ blkpart) {
  __shared__ float red[256];
  const int gid = blockIdx.x * 256 + threadIdx.x;
  const int stride = RED_BLOCKS * 256;
  float s = 0.0f;
  for (int r = gid; r < TWO_B; r += stride) s += 8.0f * logf(rowsum[r] + LOSS_EPS);
  for (int k = gid; k < N_POS; k += stride) s -= pos_partial[k];
  red[threadIdx.x] = s;
  __syncthreads();
  for (int st = 128; st > 0; st >>= 1) {
    if (threadIdx.x < st) red[threadIdx.x] += red[threadIdx.x + st];
    __syncthreads();
  }
  if (threadIdx.x == 0) blkpart[blockIdx.x] = red[0];
}

// ---------------- K4b: final scalar ----------------
__global__ __launch_bounds__(64) void k_final(
    const float* __restrict__ blkpart, float* __restrict__ out) {
  float s = threadIdx.x < RED_BLOCKS ? blkpart[threadIdx.x] : 0.0f;
#pragma unroll
  for (int m = 1; m < 64; m <<= 1) s += __shfl_xor(s, m, 64);
  if (threadIdx.x == 0) out[0] = s * (1.0f / 65536.0f);
}

extern "C" void kernel_launch(void* const* d_in, const int* in_sizes, int n_in,
                              void* d_out, int out_size, void* d_ws, size_t ws_size,
                              hipStream_t stream) {
  const float* z1 = (const float*)d_in[0];
  const float* z2 = (const float*)d_in[1];
  const float* zn = (const float*)d_in[2];
  float* out = (float*)d_out;

  char* ws = (char*)d_ws;
  __hip_bfloat16* za_n = (__hip_bfloat16*)ws;                          // 2 MB
  float* inv_za = (float*)(ws + 2097152);                              // 32 KB
  float* inv_zn = (float*)(ws + 2097152 + 32768);                      // 64 KB
  float* rowsum = (float*)(ws + 2097152 + 32768 + 65536);              // 32 KB
  float* pos_partial = (float*)(ws + 2097152 + 32768 + 65536 + 32768); // 160 KB
  float* blkpart = (float*)(ws + 2097152 + 32768 + 65536 + 32768 + 163840); // 256 B

  // K1: normalize + zero rowsum (24576 waves, 4/block)
  k_normalize<<<(TWO_B + NB) / 4, 256, 0, stream>>>(z1, z2, zn, za_n, inv_za, inv_zn, rowsum);
  // K2: positives, 8 dots/wave -> 1280 blocks
  k_positives<<<(N_POS / 8 + 3) / 4, 256, 0, stream>>>(z1, z2, zn, inv_za, inv_zn, pos_partial);
  // K3: symmetric gram row/col sums
  k_gram<<<GRAM_BLOCKS, 512, 0, stream>>>(za_n, rowsum);
  // K4: two-stage reduction
  k_reduce<<<RED_BLOCKS, 256, 0, stream>>>(rowsum, pos_partial, blkpart);
  k_final<<<1, 64, 0, stream>>>(blkpart, out);
}

// Round 6
// 55.926 us; speedup vs baseline: 1.1021x; 1.1021x over previous
//
#include <hip/hip_runtime.h>
#include <hip/hip_bf16.h>
#include <math.h>

#define BATCH 4096
#define TWO_B 8192
#define DIM 128
#define NB 16384
#define COS_EPS 1e-8f
#define LOSS_EPS 1e-6f
// 1/TEMP ; log2(e)/TEMP ; sqrt(log2(e)/TEMP)
#define INV_TEMP 14.285714285714286f
#define EXP2_SCALE 20.60992915555662f
#define SQRT_EXP2_SCALE 4.5398166f

#define N_POS (TWO_B + 8 * BATCH)   // 40960 positive dots
#define RED_BLOCKS 64
#define GRAM_BLOCKS 2080            // #{(I,J): 0<=I<=J<64}

typedef __attribute__((ext_vector_type(8))) short bf16x8;
typedef __attribute__((ext_vector_type(4))) float f32x4;

__device__ __forceinline__ float fast_exp2(float x) {
#if __has_builtin(__builtin_amdgcn_exp2f)
  return __builtin_amdgcn_exp2f(x);
#else
  float r;
  asm("v_exp_f32 %0, %1" : "=v"(r) : "v"(x));
  return r;
#endif
}

// ---------------- K1: normalize rows -> bf16 za_n (pre-scaled), inv norms; zero rowsum ----------------
__global__ __launch_bounds__(256) void k_normalize(
    const float* __restrict__ z1, const float* __restrict__ z2,
    const float* __restrict__ zn,
    __hip_bfloat16* __restrict__ za_n, float* __restrict__ inv_za,
    float* __restrict__ inv_zn, float* __restrict__ rowsum) {
  if (blockIdx.x < 32) rowsum[blockIdx.x * 256 + threadIdx.x] = 0.0f;  // fused zero
  int wave = (blockIdx.x * blockDim.x + threadIdx.x) >> 6;
  int lane = threadIdx.x & 63;
  if (wave >= TWO_B + NB) return;
  const float* src;
  if (wave < BATCH) src = z1 + (size_t)wave * DIM;
  else if (wave < TWO_B) src = z2 + (size_t)(wave - BATCH) * DIM;
  else src = zn + (size_t)(wave - TWO_B) * DIM;
  float2 v = ((const float2*)src)[lane];
  float ss = v.x * v.x + v.y * v.y;
#pragma unroll
  for (int m = 1; m < 64; m <<= 1) ss += __shfl_xor(ss, m, 64);
  float inv = 1.0f / fmaxf(sqrtf(ss), COS_EPS);
  if (wave < TWO_B) {
    if (lane == 0) inv_za[wave] = inv;
    float s = inv * SQRT_EXP2_SCALE;   // fold exp2 scale into the data
    __hip_bfloat162 o;
    o.x = __float2bfloat16(v.x * s);
    o.y = __float2bfloat16(v.y * s);
    ((__hip_bfloat162*)(za_n + (size_t)wave * DIM))[lane] = o;
  } else {
    if (lane == 0) inv_zn[wave - TWO_B] = inv;
  }
}

// ---------------- K2: positives, 8 dots per wave (8-lane sub-groups), fp32 exact ----------------
__device__ __forceinline__ const float* za_row(const float* z1, const float* z2, int r) {
  return r < BATCH ? z1 + (size_t)r * DIM : z2 + (size_t)(r - BATCH) * DIM;
}

__global__ __launch_bounds__(256) void k_positives(
    const float* __restrict__ z1, const float* __restrict__ z2,
    const float* __restrict__ zn, const float* __restrict__ inv_za,
    const float* __restrict__ inv_zn, float* __restrict__ pos_partial) {
  int wv = (blockIdx.x * 256 + threadIdx.x) >> 6;
  int lane = threadIdx.x & 63;
  int p = lane >> 3, sub = lane & 7;
  int idx = wv * 8 + p;
  if (idx >= N_POS) return;
  const float *pa, *pb;
  float invprod;
  bool is_aug;
  if (idx < TWO_B) {
    int r = idx, q = (idx + BATCH) & (TWO_B - 1);
    pa = za_row(z1, z2, r);
    pb = za_row(z1, z2, q);
    invprod = inv_za[r] * inv_za[q];
    is_aug = true;
  } else {
    int k = idx - TWO_B;
    int zr, zc;
    if (k < BATCH)                { zr = BATCH + k; zc = k; }
    else if (k < BATCH + TWO_B)   { int j = k - BATCH;             zr = j; zc = j; }
    else if (k < BATCH + 2*TWO_B) { int j = k - BATCH - TWO_B;     zr = j; zc = j + BATCH; }
    else if (k < BATCH + 3*TWO_B) { int j = k - BATCH - 2*TWO_B;   zr = j; zc = j + 2*BATCH; }
    else                          { int j = k - BATCH - 3*TWO_B;   zr = j; zc = j + 3*BATCH; }
    pa = za_row(z1, z2, zr);
    pb = zn + (size_t)zc * DIM;
    invprod = inv_za[zr] * inv_zn[zc];
    is_aug = false;
  }
  float d = 0.0f;
#pragma unroll
  for (int j = 0; j < 4; ++j) {
    float4 a = ((const float4*)pa)[sub + j * 8];
    float4 b = ((const float4*)pb)[sub + j * 8];
    d += a.x * b.x + a.y * b.y + a.z * b.z + a.w * b.w;
  }
  d += __shfl_xor(d, 1, 64);
  d += __shfl_xor(d, 2, 64);
  d += __shfl_xor(d, 4, 64);
  if (sub == 0) {
    float sim = d * invprod;
    pos_partial[idx] = is_aug ? (4.0f * sim * INV_TEMP)
                              : (fminf(sim, 1.0f) * INV_TEMP);
  }
}

// ---------------- K3: symmetric Gram, 128x128 tiles (I<=J), strict-upper mask, row+col sums ----------------
// grid: 2080 blocks; block 256 thr = 4 waves of 64x64; LDS 32 KB (K split in 2 halves).
__global__ __launch_bounds__(256) void k_gram(
    const __hip_bfloat16* __restrict__ za_n, float* __restrict__ rowsum) {
  __shared__ char ldsA[16384];
  __shared__ char ldsB[16384];
  const int t = threadIdx.x;
  int rem = blockIdx.x, I = 0;
  while (rem >= 64 - I) { rem -= 64 - I; ++I; }
  const int J = I + rem;
  const int Ibase = I * 128, Jbase = J * 128;
  const char* za8 = (const char*)za_n;   // byte view; row stride 256 B

  const int w = t >> 6, lane = t & 63;
  const int wr = w & 1, wc = w >> 1;     // 2x2 waves of 64x64
  const int lhi = lane >> 4, llo = lane & 15;

  f32x4 acc[4][4];
#pragma unroll
  for (int rt = 0; rt < 4; ++rt)
#pragma unroll
    for (int ct = 0; ct < 4; ++ct) acc[rt][ct] = (f32x4)0.0f;

  for (int h = 0; h < 2; ++h) {
    if (h) __syncthreads();              // half-0 reads complete before overwrite
    // stage A half: 128 rows x 128 B (64 k-elems), XOR-swizzled
#pragma unroll
    for (int it = 0; it < 4; ++it) {
      int e = it * 4096 + t * 16;
      int row = e >> 7, kb = e & 127;
      uint4 d = *(const uint4*)(za8 + (size_t)(Ibase + row) * 256 + h * 128 + kb);
      *(uint4*)(ldsA + row * 128 + (kb ^ ((row & 7) << 4))) = d;
    }
    // stage B half: 128 rows x 128 B
#pragma unroll
    for (int it = 0; it < 4; ++it) {
      int e = it * 4096 + t * 16;
      int row = e >> 7, kb = e & 127;
      uint4 d = *(const uint4*)(za8 + (size_t)(Jbase + row) * 256 + h * 128 + kb);
      *(uint4*)(ldsB + row * 128 + (kb ^ ((row & 7) << 4))) = d;
    }
    __syncthreads();
#pragma unroll
    for (int ks = 0; ks < 2; ++ks) {
      const int koff = ks * 64 + lhi * 16;    // byte offset within 128B row
      bf16x8 af[4], bfr[4];
#pragma unroll
      for (int rt = 0; rt < 4; ++rt) {
        int row = wr * 64 + rt * 16 + llo;
        af[rt] = *(const bf16x8*)(ldsA + row * 128 + (koff ^ ((row & 7) << 4)));
      }
#pragma unroll
      for (int ct = 0; ct < 4; ++ct) {
        int row = wc * 64 + ct * 16 + llo;
        bfr[ct] = *(const bf16x8*)(ldsB + row * 128 + (koff ^ ((row & 7) << 4)));
      }
#pragma unroll
      for (int rt = 0; rt < 4; ++rt)
#pragma unroll
        for (int ct = 0; ct < 4; ++ct)
          acc[rt][ct] = __builtin_amdgcn_mfma_f32_16x16x32_bf16(
              af[rt], bfr[ct], acc[rt][ct], 0, 0, 0);
    }
  }

  // epilogue: exp2, strict-upper mask (covers diagonal tiles; off-diag all true), row+col sums
  float cp[4] = {0.0f, 0.0f, 0.0f, 0.0f};
#pragma unroll
  for (int rt = 0; rt < 4; ++rt) {
    const int growb = Ibase + wr * 64 + rt * 16 + lhi * 4;   // + g
    float rp[4] = {0.0f, 0.0f, 0.0f, 0.0f};
#pragma unroll
    for (int ct = 0; ct < 4; ++ct) {
      const int gcol = Jbase + wc * 64 + ct * 16 + llo;
#pragma unroll
      for (int g = 0; g < 4; ++g) {
        float e = fast_exp2(acc[rt][ct][g]);
        e = (gcol > growb + g) ? e : 0.0f;   // strict upper triangle only
        rp[g] += e;
        cp[ct] += e;
      }
    }
#pragma unroll
    for (int g = 0; g < 4; ++g) {
      float s = rp[g];
      s += __shfl_xor(s, 1, 64);
      s += __shfl_xor(s, 2, 64);
      s += __shfl_xor(s, 4, 64);
      s += __shfl_xor(s, 8, 64);
      if (llo == 0) atomicAdd(&rowsum[growb + g], s);
    }
  }
#pragma unroll
  for (int ct = 0; ct < 4; ++ct) {
    float s = cp[ct];
    s += __shfl_xor(s, 16, 64);
    s += __shfl_xor(s, 32, 64);
    if (lhi == 0) atomicAdd(&rowsum[Jbase + wc * 64 + ct * 16 + llo], s);
  }
}

// ---------------- K4a: parallel reduction stage 1 ----------------
__global__ __launch_bounds__(256) void k_reduce(
    const float* __restrict__ rowsum, const float* __restrict__ pos_partial,
    float* __restrict__ blkpart) {
  __shared__ float red[256];
  const int gid = blockIdx.x * 256 + threadIdx.x;
  const int stride = RED_BLOCKS * 256;
  float s = 0.0f;
  for (int r = gid; r < TWO_B; r += stride) s += 8.0f * logf(rowsum[r] + LOSS_EPS);
  for (int k = gid; k < N_POS; k += stride) s -= pos_partial[k];
  red[threadIdx.x] = s;
  __syncthreads();
  for (int st = 128; st > 0; st >>= 1) {
    if (threadIdx.x < st) red[threadIdx.x] += red[threadIdx.x + st];
    __syncthreads();
  }
  if (threadIdx.x == 0) blkpart[blockIdx.x] = red[0];
}

// ---------------- K4b: final scalar ----------------
__global__ __launch_bounds__(64) void k_final(
    const float* __restrict__ blkpart, float* __restrict__ out) {
  float s = threadIdx.x < RED_BLOCKS ? blkpart[threadIdx.x] : 0.0f;
#pragma unroll
  for (int m = 1; m < 64; m <<= 1) s += __shfl_xor(s, m, 64);
  if (threadIdx.x == 0) out[0] = s * (1.0f / 65536.0f);
}

extern "C" void kernel_launch(void* const* d_in, const int* in_sizes, int n_in,
                              void* d_out, int out_size, void* d_ws, size_t ws_size,
                              hipStream_t stream) {
  const float* z1 = (const float*)d_in[0];
  const float* z2 = (const float*)d_in[1];
  const float* zn = (const float*)d_in[2];
  float* out = (float*)d_out;

  char* ws = (char*)d_ws;
  __hip_bfloat16* za_n = (__hip_bfloat16*)ws;                          // 2 MB
  float* inv_za = (float*)(ws + 2097152);                              // 32 KB
  float* inv_zn = (float*)(ws + 2097152 + 32768);                      // 64 KB
  float* rowsum = (float*)(ws + 2097152 + 32768 + 65536);              // 32 KB
  float* pos_partial = (float*)(ws + 2097152 + 32768 + 65536 + 32768); // 160 KB
  float* blkpart = (float*)(ws + 2097152 + 32768 + 65536 + 32768 + 163840); // 256 B

  // K1: normalize + zero rowsum (24576 waves, 4/block)
  k_normalize<<<(TWO_B + NB) / 4, 256, 0, stream>>>(z1, z2, zn, za_n, inv_za, inv_zn, rowsum);
  // K2: positives, 8 dots/wave
  k_positives<<<(N_POS / 8 + 3) / 4, 256, 0, stream>>>(z1, z2, zn, inv_za, inv_zn, pos_partial);
  // K3: symmetric gram row/col sums, one block per upper-tri 128x128 tile
  k_gram<<<GRAM_BLOCKS, 256, 0, stream>>>(za_n, rowsum);
  // K4: two-stage reduction
  k_reduce<<<RED_BLOCKS, 256, 0, stream>>>(rowsum, pos_partial, blkpart);
  k_final<<<1, 64, 0, stream>>>(blkpart, out);
}